// Round 3
// baseline (590.011 us; speedup 1.0000x reference)
//
#include <hip/hip_runtime.h>

// Problem constants: B=1, N=3, C=128, H=W=256, HEADS=4, hd=32, SCALES=[16,8,4]

typedef __attribute__((ext_vector_type(8))) short bf16x8;
typedef __attribute__((ext_vector_type(4))) float f32x4;

__device__ inline ushort rne_bf16(float x) {
  uint u = __float_as_uint(x);
  return (ushort)((u + 0x7fffu + ((u >> 16) & 1u)) >> 16);
}

// ---------------- pool by 4: query/keys/values -> pooled4 [7][128][64][64]
__global__ __launch_bounds__(256) void pool4_kernel(
    const float* __restrict__ query, const float* __restrict__ keys,
    const float* __restrict__ values, float* __restrict__ out)
{
  int idx = blockIdx.x * 256 + threadIdx.x;      // [0, 7*128*4096)
  int x = idx & 63, y = (idx >> 6) & 63, mc = idx >> 12;   // mc = map*128 + c
  int map = mc >> 7, c = mc & 127;
  const float* src;
  if (map == 0)      src = query  + (size_t)c * 65536;
  else if (map <= 3) src = keys   + (size_t)((map - 1) * 128 + c) * 65536;
  else               src = values + (size_t)((map - 4) * 128 + c) * 65536;
  src += (y * 4) * 256 + x * 4;
  float s = 0.f;
#pragma unroll
  for (int r = 0; r < 4; ++r) {
    float4 v = *(const float4*)(src + r * 256);
    s += v.x + v.y + v.z + v.w;
  }
  out[idx] = s * 0.0625f;
}

// ---------------- pool by 2 (generic): [896][2w][2w] -> [896][w][w]
__global__ __launch_bounds__(256) void pool2_kernel(
    const float* __restrict__ in, float* __restrict__ out, int hw)
{
  int idx = blockIdx.x * 256 + threadIdx.x;
  int x = idx % hw; int y = (idx / hw) % hw; int mc = idx / (hw * hw);
  int w2 = hw * 2;
  const float* s = in + (size_t)mc * w2 * w2 + (2 * y) * w2 + 2 * x;
  float2 a = *(const float2*)s;
  float2 b = *(const float2*)(s + w2);
  out[idx] = (a.x + a.y + b.x + b.y) * 0.25f;
}

// ---------------- precompute Wc = out_w @ fusion_w  [128][384], bc = out_b + out_w @ fusion_b
__global__ __launch_bounds__(256) void precomp_kernel(
    const float* __restrict__ fusion_w, const float* __restrict__ fusion_b,
    const float* __restrict__ out_w, const float* __restrict__ out_b,
    float* __restrict__ Wc, float* __restrict__ bc)
{
  int idx = blockIdx.x * 256 + threadIdx.x;
  if (idx < 128 * 384) {
    int o = idx / 384, k = idx % 384;
    float s = 0.f;
    for (int c = 0; c < 128; ++c)
      s = fmaf(out_w[o * 128 + c], fusion_w[c * 384 + k], s);
    Wc[idx] = s;
  } else if (idx < 128 * 384 + 128) {
    int o = idx - 128 * 384;
    float s = out_b[o];
    for (int c = 0; c < 128; ++c)
      s = fmaf(out_w[o * 128 + c], fusion_b[c], s);
    bc[o] = s;
  }
}

// ---------------- 1x1 conv projection -> bf16 operand arrays in MFMA layouts
// map 0: qb[head][L][32] (scaled);  maps 1-3: kb[a][head][L][32]; maps 4-6: vb[a][c][L]
__global__ __launch_bounds__(256) void proj_kernel(
    const float* __restrict__ pooled,
    ushort* __restrict__ qb, ushort* __restrict__ kbb, ushort* __restrict__ vbb,
    const float* __restrict__ wq, const float* __restrict__ bq,
    const float* __restrict__ wk, const float* __restrict__ bk,
    const float* __restrict__ wv, const float* __restrict__ bv,
    int si, int L, float qscale)
{
  __shared__ float Wt[32][68];
  __shared__ float Xs[32][64];
  int map = blockIdx.z;
  int o0 = blockIdx.y * 64;
  int l0 = blockIdx.x * 64;
  const float* w; const float* b; float sc = 1.f;
  if (map == 0)      { w = wq + si * 16384; b = bq + si * 128; sc = qscale; }
  else if (map <= 3) { w = wk + si * 16384; b = bk + si * 128; }
  else               { w = wv + si * 16384; b = bv + si * 128; }
  const float* src = pooled + (size_t)map * 128 * L;
  int t = threadIdx.x;
  int og = t >> 4, lg = t & 15;
  float acc[4][4] = {};
  for (int c0 = 0; c0 < 128; c0 += 32) {
    __syncthreads();
    { // stage W[64 o][32 c] -> Wt[c][o]
      int o = t >> 2, ci = (t & 3) * 8;
      const float* wp = w + (o0 + o) * 128 + c0 + ci;
      float4 a = *(const float4*)wp, d = *(const float4*)(wp + 4);
      Wt[ci + 0][o] = a.x; Wt[ci + 1][o] = a.y; Wt[ci + 2][o] = a.z; Wt[ci + 3][o] = a.w;
      Wt[ci + 4][o] = d.x; Wt[ci + 5][o] = d.y; Wt[ci + 6][o] = d.z; Wt[ci + 7][o] = d.w;
    }
    { // stage X[32 c][64 l]
      int c = t >> 3, li = (t & 7) * 8;
      const float* xp = src + (size_t)(c0 + c) * L + l0 + li;
      float4 a = *(const float4*)xp, d = *(const float4*)(xp + 4);
      *(float4*)&Xs[c][li] = a; *(float4*)&Xs[c][li + 4] = d;
    }
    __syncthreads();
#pragma unroll 8
    for (int k = 0; k < 32; ++k) {
      float4 wv4 = *(const float4*)&Wt[k][4 * og];
      float4 xv4 = *(const float4*)&Xs[k][4 * lg];
      float wa[4] = {wv4.x, wv4.y, wv4.z, wv4.w};
      float xa[4] = {xv4.x, xv4.y, xv4.z, xv4.w};
#pragma unroll
      for (int r = 0; r < 4; ++r)
#pragma unroll
        for (int c = 0; c < 4; ++c)
          acc[r][c] = fmaf(wa[r], xa[c], acc[r][c]);
    }
  }
  float4 b4 = *(const float4*)&b[o0 + 4 * og];
  float ba[4] = {b4.x, b4.y, b4.z, b4.w};
  if (map < 4) {
    ushort* dst = (map == 0) ? qb : (kbb + (size_t)(map - 1) * L * 32 * 4);
    int o4 = o0 + 4 * og;
    size_t hbase = (size_t)(o4 >> 5) * L * 32 + (o4 & 31);
#pragma unroll
    for (int li = 0; li < 4; ++li) {
      ushort4 r;
      r.x = rne_bf16((acc[0][li] + ba[0]) * sc);
      r.y = rne_bf16((acc[1][li] + ba[1]) * sc);
      r.z = rne_bf16((acc[2][li] + ba[2]) * sc);
      r.w = rne_bf16((acc[3][li] + ba[3]) * sc);
      *(ushort4*)&dst[hbase + (size_t)(l0 + 4 * lg + li) * 32] = r;
    }
  } else {
    ushort* dst = vbb + (size_t)(map - 4) * 128 * L;
#pragma unroll
    for (int oi = 0; oi < 4; ++oi) {
      ushort4 r;
      r.x = rne_bf16(acc[oi][0] + ba[oi]);
      r.y = rne_bf16(acc[oi][1] + ba[oi]);
      r.z = rne_bf16(acc[oi][2] + ba[oi]);
      r.w = rne_bf16(acc[oi][3] + ba[oi]);
      *(ushort4*)&dst[(size_t)(o0 + 4 * og + oi) * L + l0 + 4 * lg] = r;
    }
  }
}

// ---------------- MFMA flash attention, S^T form, 2 l-tiles/wave, m-split
// Accumulates UNNORMALIZED O into onum[a][c][L] and row-sums into lsum[a][h][L].
#define PSTR 72
__global__ __launch_bounds__(256, 3) void attn_mfma_kernel(
    const ushort* __restrict__ qb, const ushort* __restrict__ kb,
    const ushort* __restrict__ vb, float* __restrict__ onum,
    float* __restrict__ lsum, int L, int msplit)
{
  __shared__ __align__(16) ushort P[8][16][PSTR];
  int t = threadIdx.x;
  int wave = t >> 6, lane = t & 63;
  int col = lane & 15, quad = lane >> 4;
  int head = blockIdx.y;
  int anchor = blockIdx.z / msplit, mpart = blockIdx.z % msplit;
  int l0 = blockIdx.x * 128;
  int lA = l0 + wave * 16;
  int lB = l0 + 64 + wave * 16;
  int mlen = L / msplit, mbase = mpart * mlen;

  const ushort* qh = qb + (size_t)head * L * 32;
  const ushort* kh = kb + ((size_t)anchor * 4 + head) * L * 32;
  const ushort* vh = vb + (size_t)anchor * 128 * L + (size_t)head * 32 * L;

  bf16x8 qfA = *(const bf16x8*)(qh + (size_t)(lA + col) * 32 + quad * 8);
  bf16x8 qfB = *(const bf16x8*)(qh + (size_t)(lB + col) * 32 + quad * 8);

  f32x4 oA0 = {0.f,0.f,0.f,0.f}, oA1 = {0.f,0.f,0.f,0.f};
  f32x4 oB0 = {0.f,0.f,0.f,0.f}, oB1 = {0.f,0.f,0.f,0.f};
  float lsA = 0.f, lsB = 0.f;
  ushort* PA = &P[wave * 2 + 0][0][0];
  ushort* PB = &P[wave * 2 + 1][0][0];
  const f32x4 z = {0.f,0.f,0.f,0.f};

  for (int mo = 0; mo < mlen; mo += 64) {
    int m0 = mbase + mo;
    const ushort* kp = kh + (size_t)(m0 + col) * 32 + quad * 8;
    bf16x8 k0 = *(const bf16x8*)(kp);
    bf16x8 k1 = *(const bf16x8*)(kp + 16 * 32);
    bf16x8 k2 = *(const bf16x8*)(kp + 32 * 32);
    bf16x8 k3 = *(const bf16x8*)(kp + 48 * 32);
    const ushort* vp = vh + (size_t)col * L + m0 + quad * 8;
    bf16x8 v00 = *(const bf16x8*)(vp);
    bf16x8 v01 = *(const bf16x8*)(vp + 32);
    bf16x8 v10 = *(const bf16x8*)(vp + (size_t)16 * L);
    bf16x8 v11 = *(const bf16x8*)(vp + (size_t)16 * L + 32);

    // S^T tiles: D[m-within-tile][l], A=K, B=Q
    f32x4 sA[4], sB[4];
    sA[0] = __builtin_amdgcn_mfma_f32_16x16x32_bf16(k0, qfA, z, 0, 0, 0);
    sA[1] = __builtin_amdgcn_mfma_f32_16x16x32_bf16(k1, qfA, z, 0, 0, 0);
    sA[2] = __builtin_amdgcn_mfma_f32_16x16x32_bf16(k2, qfA, z, 0, 0, 0);
    sA[3] = __builtin_amdgcn_mfma_f32_16x16x32_bf16(k3, qfA, z, 0, 0, 0);
    sB[0] = __builtin_amdgcn_mfma_f32_16x16x32_bf16(k0, qfB, z, 0, 0, 0);
    sB[1] = __builtin_amdgcn_mfma_f32_16x16x32_bf16(k1, qfB, z, 0, 0, 0);
    sB[2] = __builtin_amdgcn_mfma_f32_16x16x32_bf16(k2, qfB, z, 0, 0, 0);
    sB[3] = __builtin_amdgcn_mfma_f32_16x16x32_bf16(k3, qfB, z, 0, 0, 0);

    // p = exp(s), truncate to bf16, sum TRUNCATED values; pack 4 m-consecutive
    // bf16 into one b64 LDS write at P[l=col][m = 16j + quad*4]
#pragma unroll
    for (int j = 0; j < 4; ++j) {
      uint b0 = __float_as_uint(__expf(sA[j][0])) & 0xffff0000u;
      uint b1 = __float_as_uint(__expf(sA[j][1])) & 0xffff0000u;
      uint b2 = __float_as_uint(__expf(sA[j][2])) & 0xffff0000u;
      uint b3 = __float_as_uint(__expf(sA[j][3])) & 0xffff0000u;
      lsA += __uint_as_float(b0) + __uint_as_float(b1) +
             __uint_as_float(b2) + __uint_as_float(b3);
      uint2 dw;
      dw.x = (b0 >> 16) | b1;
      dw.y = (b2 >> 16) | b3;
      *(uint2*)&PA[col * PSTR + 16 * j + quad * 4] = dw;
    }
#pragma unroll
    for (int j = 0; j < 4; ++j) {
      uint b0 = __float_as_uint(__expf(sB[j][0])) & 0xffff0000u;
      uint b1 = __float_as_uint(__expf(sB[j][1])) & 0xffff0000u;
      uint b2 = __float_as_uint(__expf(sB[j][2])) & 0xffff0000u;
      uint b3 = __float_as_uint(__expf(sB[j][3])) & 0xffff0000u;
      lsB += __uint_as_float(b0) + __uint_as_float(b1) +
             __uint_as_float(b2) + __uint_as_float(b3);
      uint2 dw;
      dw.x = (b0 >> 16) | b1;
      dw.y = (b2 >> 16) | b3;
      *(uint2*)&PB[col * PSTR + 16 * j + quad * 4] = dw;
    }

    // P A-frags (row l=col, k-chunks of m) and PV
    bf16x8 pA0 = *(const bf16x8*)(&PA[col * PSTR + quad * 8]);
    bf16x8 pA1 = *(const bf16x8*)(&PA[col * PSTR + 32 + quad * 8]);
    bf16x8 pB0 = *(const bf16x8*)(&PB[col * PSTR + quad * 8]);
    bf16x8 pB1 = *(const bf16x8*)(&PB[col * PSTR + 32 + quad * 8]);
    oA0 = __builtin_amdgcn_mfma_f32_16x16x32_bf16(pA0, v00, oA0, 0, 0, 0);
    oA0 = __builtin_amdgcn_mfma_f32_16x16x32_bf16(pA1, v01, oA0, 0, 0, 0);
    oA1 = __builtin_amdgcn_mfma_f32_16x16x32_bf16(pA0, v10, oA1, 0, 0, 0);
    oA1 = __builtin_amdgcn_mfma_f32_16x16x32_bf16(pA1, v11, oA1, 0, 0, 0);
    oB0 = __builtin_amdgcn_mfma_f32_16x16x32_bf16(pB0, v00, oB0, 0, 0, 0);
    oB0 = __builtin_amdgcn_mfma_f32_16x16x32_bf16(pB1, v01, oB0, 0, 0, 0);
    oB1 = __builtin_amdgcn_mfma_f32_16x16x32_bf16(pB0, v10, oB1, 0, 0, 0);
    oB1 = __builtin_amdgcn_mfma_f32_16x16x32_bf16(pB1, v11, oB1, 0, 0, 0);
  }

  // row-sum butterfly over quads (lane bits 4,5); all lanes of a col converge
  lsA += __shfl_xor(lsA, 16); lsA += __shfl_xor(lsA, 32);
  lsB += __shfl_xor(lsB, 16); lsB += __shfl_xor(lsB, 32);
  float* lsp = lsum + ((size_t)anchor * 4 + head) * L;
  if (quad == 0) {
    atomicAdd(&lsp[lA + col], lsA);
    atomicAdd(&lsp[lB + col], lsB);
  }
  float* on = onum + (size_t)anchor * 128 * L + (size_t)(head * 32) * L;
#pragma unroll
  for (int r = 0; r < 4; ++r) {
    atomicAdd(&on[(size_t)col * L + lA + quad * 4 + r],        oA0[r]);
    atomicAdd(&on[(size_t)(16 + col) * L + lA + quad * 4 + r], oA1[r]);
    atomicAdd(&on[(size_t)col * L + lB + quad * 4 + r],        oB0[r]);
    atomicAdd(&on[(size_t)(16 + col) * L + lB + quad * 4 + r], oB1[r]);
  }
}

// ---------------- normalize: A[c][l] = (1/3) * sum_a onum[a][c][l] / lsum[a][h][l]
__global__ __launch_bounds__(256) void norm_kernel(
    const float* __restrict__ on4,  const float* __restrict__ ls4,  float* __restrict__ a4,
    const float* __restrict__ on8,  const float* __restrict__ ls8,  float* __restrict__ a8,
    const float* __restrict__ on16, const float* __restrict__ ls16, float* __restrict__ a16)
{
  int i = blockIdx.x * 256 + threadIdx.x;   // float4 index
  const float* on; const float* ls; float* ax; int L;
  if (i < 131072)      { on = on4;  ls = ls4;  ax = a4;  L = 4096; }
  else if (i < 163840) { i -= 131072; on = on8;  ls = ls8;  ax = a8;  L = 1024; }
  else                 { i -= 163840; on = on16; ls = ls16; ax = a16; L = 256; }
  int e = i * 4;
  int c = e / L, l = e % L;
  int h = c >> 5;
  float ax0 = 0.f, ax1 = 0.f, ax2 = 0.f, ax3 = 0.f;
#pragma unroll
  for (int a = 0; a < 3; ++a) {
    float4 o = *(const float4*)&on[(size_t)(a * 128 + c) * L + l];
    float4 s = *(const float4*)&ls[(size_t)(a * 4 + h) * L + l];
    ax0 += o.x / s.x; ax1 += o.y / s.y; ax2 += o.z / s.z; ax3 += o.w / s.w;
  }
  const float third = 1.f / 3.f;
  float4 r = make_float4(ax0 * third, ax1 * third, ax2 * third, ax3 * third);
  *(float4*)&ax[e] = r;
}

// ---------------- fused bilinear upsample + combined 1x1 conv
__global__ __launch_bounds__(256) void fuse_kernel(
    const float* __restrict__ a16, const float* __restrict__ a8,
    const float* __restrict__ a4, const float* __restrict__ Wc,
    const float* __restrict__ bc, float* __restrict__ outp)
{
  __shared__ float Wt[32][132];
  __shared__ float Xs[32][64];
  __shared__ float patch[32][16];
  int t = threadIdx.x;
  int px0 = blockIdx.x * 8, py0 = blockIdx.y * 8;
  int og = t >> 3, pg = t & 7;
  float acc[4][8] = {};
  for (int ch = 0; ch < 12; ++ch) {
    int sci = ch >> 2;
    int coff = (ch & 3) * 32;
    int ssz; const float* src; float sf;
    if (sci == 0)      { ssz = 16; src = a16; sf = 1.f / 16.f; }
    else if (sci == 1) { ssz = 32; src = a8;  sf = 1.f / 8.f; }
    else               { ssz = 64; src = a4;  sf = 1.f / 4.f; }
    float sx0 = (px0 + 0.5f) * sf - 0.5f;
    float sy0 = (py0 + 0.5f) * sf - 0.5f;
    int x0f = (int)floorf(sx0);
    int y0f = (int)floorf(sy0);
    __syncthreads();
    { // stage Wc chunk -> Wt[k][o]
      int o = t >> 1, ki = (t & 1) * 16;
      const float* wp = Wc + o * 384 + ch * 32 + ki;
#pragma unroll
      for (int j = 0; j < 16; j += 4) {
        float4 w4 = *(const float4*)(wp + j);
        Wt[ki + j + 0][o] = w4.x; Wt[ki + j + 1][o] = w4.y;
        Wt[ki + j + 2][o] = w4.z; Wt[ki + j + 3][o] = w4.w;
      }
    }
    if (t < 128) { // stage 4x4 source patch for 32 channels
      int c = t >> 2, ry = t & 3;
      int yy = min(max(y0f + ry, 0), ssz - 1);
      const float* sp = src + (size_t)(coff + c) * ssz * ssz + yy * ssz;
#pragma unroll
      for (int rx = 0; rx < 4; ++rx) {
        int xx = min(max(x0f + rx, 0), ssz - 1);
        patch[c][ry * 4 + rx] = sp[xx];
      }
    }
    __syncthreads();
    { // bilinear -> Xs[k][p]
      int p = t & 63, cg = t >> 6;
      int px = p & 7, py = p >> 3;
      float sx = (px0 + px + 0.5f) * sf - 0.5f;
      float sy = (py0 + py + 0.5f) * sf - 0.5f;
      int xi = (int)floorf(sx), yi = (int)floorf(sy);
      float fx = sx - xi, fy = sy - yi;
      int lx = xi - x0f, ly = yi - y0f;
      int lx1 = min(xi + 1, ssz - 1) - x0f;
      int ly1 = min(yi + 1, ssz - 1) - y0f;
      float w00 = (1.f - fy) * (1.f - fx), w01 = (1.f - fy) * fx;
      float w10 = fy * (1.f - fx), w11 = fy * fx;
#pragma unroll
      for (int j = 0; j < 8; ++j) {
        int k = 8 * cg + j;
        float v = w00 * patch[k][ly * 4 + lx] + w01 * patch[k][ly * 4 + lx1]
                + w10 * patch[k][ly1 * 4 + lx] + w11 * patch[k][ly1 * 4 + lx1];
        Xs[k][p] = v;
      }
    }
    __syncthreads();
#pragma unroll 8
    for (int k = 0; k < 32; ++k) {
      float4 w4 = *(const float4*)&Wt[k][4 * og];
      float4 xa4 = *(const float4*)&Xs[k][8 * pg];
      float4 xb4 = *(const float4*)&Xs[k][8 * pg + 4];
      float wa[4] = {w4.x, w4.y, w4.z, w4.w};
      float xv[8] = {xa4.x, xa4.y, xa4.z, xa4.w, xb4.x, xb4.y, xb4.z, xb4.w};
#pragma unroll
      for (int r = 0; r < 4; ++r)
#pragma unroll
        for (int c = 0; c < 8; ++c)
          acc[r][c] = fmaf(wa[r], xv[c], acc[r][c]);
    }
  }
#pragma unroll
  for (int oi = 0; oi < 4; ++oi) {
    int o = 4 * og + oi;
    float bb = bc[o];
    float4 r0 = make_float4(acc[oi][0] + bb, acc[oi][1] + bb, acc[oi][2] + bb, acc[oi][3] + bb);
    float4 r1 = make_float4(acc[oi][4] + bb, acc[oi][5] + bb, acc[oi][6] + bb, acc[oi][7] + bb);
    float* op = outp + (size_t)o * 65536 + (py0 + pg) * 256 + px0;
    *(float4*)op = r0; *(float4*)(op + 4) = r1;
  }
}

extern "C" void kernel_launch(void* const* d_in, const int* in_sizes, int n_in,
                              void* d_out, int out_size, void* d_ws, size_t ws_size,
                              hipStream_t stream) {
  const float* query    = (const float*)d_in[0];
  const float* keys     = (const float*)d_in[1];
  const float* values   = (const float*)d_in[2];
  const float* wq       = (const float*)d_in[3];
  const float* bq       = (const float*)d_in[4];
  const float* wk       = (const float*)d_in[5];
  const float* bk       = (const float*)d_in[6];
  const float* wv       = (const float*)d_in[7];
  const float* bv       = (const float*)d_in[8];
  const float* fusion_w = (const float*)d_in[9];
  const float* fusion_b = (const float*)d_in[10];
  const float* out_w    = (const float*)d_in[11];
  const float* out_b    = (const float*)d_in[12];
  float* wsf  = (float*)d_ws;
  float* outp = (float*)d_out;

  // workspace layout (float units)
  const size_t P4   = 0;        // pooled s=4 [7][128][4096] (dead after proj)
  const size_t P8   = 3670016;  // pooled s=8
  const size_t P16  = 4587520;  // pooled s=16
  // ON/LS alias the pool region (zeroed after proj, stream-ordered):
  const size_t ON4  = 0;        // [3][128][4096] = 1572864
  const size_t LS4  = 1572864;  // [3][4][4096]   = 49152
  const size_t ON8  = 1622016;  // 393216
  const size_t LS8  = 2015232;  // 12288
  const size_t ON16 = 2027520;  // 98304
  const size_t LS16 = 2125824;  // 3072  -> end 2128896 (< P8 offset, safe)
  const size_t QB4  = 4816896;  // bf16 [4][4096][32]
  const size_t KB4  = 5079040;  // bf16 [3][4][4096][32]
  const size_t VB4  = 5865472;  // bf16 [3][128][4096]
  const size_t QB8  = 6651904;
  const size_t KB8  = 6717440;
  const size_t VB8  = 6914048;
  const size_t QB16 = 7110656;
  const size_t KB16 = 7127040;
  const size_t VB16 = 7176192;
  const size_t A4   = 7225344;  // fp32 [128][4096]
  const size_t A8   = 7749632;
  const size_t A16  = 7880704;
  const size_t WC   = 7913472;
  const size_t BC   = 7962624;

  precomp_kernel<<<(128*384 + 128 + 255) / 256, 256, 0, stream>>>(
      fusion_w, fusion_b, out_w, out_b, wsf + WC, wsf + BC);
  pool4_kernel<<<7*128*4096/256, 256, 0, stream>>>(query, keys, values, wsf + P4);
  pool2_kernel<<<7*128*1024/256, 256, 0, stream>>>(wsf + P4, wsf + P8, 32);
  pool2_kernel<<<7*128*256/256,  256, 0, stream>>>(wsf + P8, wsf + P16, 16);

  const float qsc = 0.17677669529663687f;  // 1/sqrt(32)
  proj_kernel<<<dim3(64, 2, 7), 256, 0, stream>>>(wsf + P4,
      (ushort*)(wsf + QB4), (ushort*)(wsf + KB4), (ushort*)(wsf + VB4),
      wq, bq, wk, bk, wv, bv, 2, 4096, qsc);
  proj_kernel<<<dim3(16, 2, 7), 256, 0, stream>>>(wsf + P8,
      (ushort*)(wsf + QB8), (ushort*)(wsf + KB8), (ushort*)(wsf + VB8),
      wq, bq, wk, bk, wv, bv, 1, 1024, qsc);
  proj_kernel<<<dim3(4, 2, 7), 256, 0, stream>>>(wsf + P16,
      (ushort*)(wsf + QB16), (ushort*)(wsf + KB16), (ushort*)(wsf + VB16),
      wq, bq, wk, bk, wv, bv, 0, 256, qsc);

  // zero ON/LS accumulators (pool region is dead once proj has run; stream-ordered)
  hipMemsetAsync(wsf + ON4, 0, (size_t)2128896 * sizeof(float), stream);

  attn_mfma_kernel<<<dim3(32, 4, 12), 256, 0, stream>>>(
      (const ushort*)(wsf + QB4), (const ushort*)(wsf + KB4),
      (const ushort*)(wsf + VB4), wsf + ON4, wsf + LS4, 4096, 4);
  attn_mfma_kernel<<<dim3(8, 4, 12), 256, 0, stream>>>(
      (const ushort*)(wsf + QB8), (const ushort*)(wsf + KB8),
      (const ushort*)(wsf + VB8), wsf + ON8, wsf + LS8, 1024, 4);
  attn_mfma_kernel<<<dim3(2, 4, 12), 256, 0, stream>>>(
      (const ushort*)(wsf + QB16), (const ushort*)(wsf + KB16),
      (const ushort*)(wsf + VB16), wsf + ON16, wsf + LS16, 256, 4);

  norm_kernel<<<672, 256, 0, stream>>>(
      wsf + ON4, wsf + LS4, wsf + A4,
      wsf + ON8, wsf + LS8, wsf + A8,
      wsf + ON16, wsf + LS16, wsf + A16);

  fuse_kernel<<<dim3(32, 32), 256, 0, stream>>>(
      wsf + A16, wsf + A8, wsf + A4, wsf + WC, wsf + BC, outp);
}

// Round 4
// 579.127 us; speedup vs baseline: 1.0188x; 1.0188x over previous
//
#include <hip/hip_runtime.h>
#include <hip/hip_bf16.h>

// Problem constants: B=1, N=3, C=128, H=W=256, HEADS=4, hd=32, SCALES=[16,8,4]

typedef __attribute__((ext_vector_type(8))) short bf16x8;
typedef __attribute__((ext_vector_type(4))) float f32x4;

__device__ inline ushort rne_bf16(float x) {
  uint u = __float_as_uint(x);
  return (ushort)((u + 0x7fffu + ((u >> 16) & 1u)) >> 16);
}

__device__ inline uint pk2_bf16(float a, float b) {
  float2 f2; f2.x = a; f2.y = b;
  __hip_bfloat162 h = __float22bfloat162_rn(f2);   // v_cvt_pk_bf16_f32
  union { __hip_bfloat162 h; uint u; } cvt; cvt.h = h;
  return cvt.u;
}

// ---------------- pool by 4: query/keys/values -> pooled4 [7][128][64][64]
__global__ __launch_bounds__(256) void pool4_kernel(
    const float* __restrict__ query, const float* __restrict__ keys,
    const float* __restrict__ values, float* __restrict__ out)
{
  int idx = blockIdx.x * 256 + threadIdx.x;      // [0, 7*128*4096)
  int x = idx & 63, y = (idx >> 6) & 63, mc = idx >> 12;   // mc = map*128 + c
  int map = mc >> 7, c = mc & 127;
  const float* src;
  if (map == 0)      src = query  + (size_t)c * 65536;
  else if (map <= 3) src = keys   + (size_t)((map - 1) * 128 + c) * 65536;
  else               src = values + (size_t)((map - 4) * 128 + c) * 65536;
  src += (y * 4) * 256 + x * 4;
  float s = 0.f;
#pragma unroll
  for (int r = 0; r < 4; ++r) {
    float4 v = *(const float4*)(src + r * 256);
    s += v.x + v.y + v.z + v.w;
  }
  out[idx] = s * 0.0625f;
}

// ---------------- pool by 2 (generic): [896][2w][2w] -> [896][w][w]
__global__ __launch_bounds__(256) void pool2_kernel(
    const float* __restrict__ in, float* __restrict__ out, int hw)
{
  int idx = blockIdx.x * 256 + threadIdx.x;
  int x = idx % hw; int y = (idx / hw) % hw; int mc = idx / (hw * hw);
  int w2 = hw * 2;
  const float* s = in + (size_t)mc * w2 * w2 + (2 * y) * w2 + 2 * x;
  float2 a = *(const float2*)s;
  float2 b = *(const float2*)(s + w2);
  out[idx] = (a.x + a.y + b.x + b.y) * 0.25f;
}

// ---------------- precompute Wc = out_w @ fusion_w  [128][384], bc = out_b + out_w @ fusion_b
__global__ __launch_bounds__(256) void precomp_kernel(
    const float* __restrict__ fusion_w, const float* __restrict__ fusion_b,
    const float* __restrict__ out_w, const float* __restrict__ out_b,
    float* __restrict__ Wc, float* __restrict__ bc)
{
  int idx = blockIdx.x * 256 + threadIdx.x;
  if (idx < 128 * 384) {
    int o = idx / 384, k = idx % 384;
    float s = 0.f;
    for (int c = 0; c < 128; ++c)
      s = fmaf(out_w[o * 128 + c], fusion_w[c * 384 + k], s);
    Wc[idx] = s;
  } else if (idx < 128 * 384 + 128) {
    int o = idx - 128 * 384;
    float s = out_b[o];
    for (int c = 0; c < 128; ++c)
      s = fmaf(out_w[o * 128 + c], fusion_b[c], s);
    bc[o] = s;
  }
}

// ---------------- 1x1 conv projection -> bf16 operand arrays in MFMA layouts
// map 0: qb[head][L][32] (scaled);  maps 1-3: kb[a][head][L][32]
// maps 4-6: vb[a][head] in MFMA-frag chunks: chunk=(m>>5)*2+(d>>4), 512 elems:
//           [d&15][ (m>>3)&3 ][ m&7 ]  -> attn reads 1 KB fully coalesced
__global__ __launch_bounds__(256) void proj_kernel(
    const float* __restrict__ pooled,
    ushort* __restrict__ qb, ushort* __restrict__ kbb, ushort* __restrict__ vbb,
    const float* __restrict__ wq, const float* __restrict__ bq,
    const float* __restrict__ wk, const float* __restrict__ bk,
    const float* __restrict__ wv, const float* __restrict__ bv,
    int si, int L, float qscale)
{
  __shared__ float Wt[32][68];
  __shared__ float Xs[32][64];
  int map = blockIdx.z;
  int o0 = blockIdx.y * 64;
  int l0 = blockIdx.x * 64;
  const float* w; const float* b; float sc = 1.f;
  if (map == 0)      { w = wq + si * 16384; b = bq + si * 128; sc = qscale; }
  else if (map <= 3) { w = wk + si * 16384; b = bk + si * 128; }
  else               { w = wv + si * 16384; b = bv + si * 128; }
  const float* src = pooled + (size_t)map * 128 * L;
  int t = threadIdx.x;
  int og = t >> 4, lg = t & 15;
  float acc[4][4] = {};
  for (int c0 = 0; c0 < 128; c0 += 32) {
    __syncthreads();
    { // stage W[64 o][32 c] -> Wt[c][o]
      int o = t >> 2, ci = (t & 3) * 8;
      const float* wp = w + (o0 + o) * 128 + c0 + ci;
      float4 a = *(const float4*)wp, d = *(const float4*)(wp + 4);
      Wt[ci + 0][o] = a.x; Wt[ci + 1][o] = a.y; Wt[ci + 2][o] = a.z; Wt[ci + 3][o] = a.w;
      Wt[ci + 4][o] = d.x; Wt[ci + 5][o] = d.y; Wt[ci + 6][o] = d.z; Wt[ci + 7][o] = d.w;
    }
    { // stage X[32 c][64 l]
      int c = t >> 3, li = (t & 7) * 8;
      const float* xp = src + (size_t)(c0 + c) * L + l0 + li;
      float4 a = *(const float4*)xp, d = *(const float4*)(xp + 4);
      *(float4*)&Xs[c][li] = a; *(float4*)&Xs[c][li + 4] = d;
    }
    __syncthreads();
#pragma unroll 8
    for (int k = 0; k < 32; ++k) {
      float4 wv4 = *(const float4*)&Wt[k][4 * og];
      float4 xv4 = *(const float4*)&Xs[k][4 * lg];
      float wa[4] = {wv4.x, wv4.y, wv4.z, wv4.w};
      float xa[4] = {xv4.x, xv4.y, xv4.z, xv4.w};
#pragma unroll
      for (int r = 0; r < 4; ++r)
#pragma unroll
        for (int c = 0; c < 4; ++c)
          acc[r][c] = fmaf(wa[r], xa[c], acc[r][c]);
    }
  }
  float4 b4 = *(const float4*)&b[o0 + 4 * og];
  float ba[4] = {b4.x, b4.y, b4.z, b4.w};
  if (map < 4) {
    ushort* dst = (map == 0) ? qb : (kbb + (size_t)(map - 1) * L * 32 * 4);
    int o4 = o0 + 4 * og;
    size_t hbase = (size_t)(o4 >> 5) * L * 32 + (o4 & 31);
#pragma unroll
    for (int li = 0; li < 4; ++li) {
      ushort4 r;
      r.x = rne_bf16((acc[0][li] + ba[0]) * sc);
      r.y = rne_bf16((acc[1][li] + ba[1]) * sc);
      r.z = rne_bf16((acc[2][li] + ba[2]) * sc);
      r.w = rne_bf16((acc[3][li] + ba[3]) * sc);
      *(ushort4*)&dst[hbase + (size_t)(l0 + 4 * lg + li) * 32] = r;
    }
  } else {
    ushort* dst = vbb + (size_t)(map - 4) * 128 * L;   // per-anchor 4 heads * 32*L
    int m = l0 + 4 * lg;                               // 4-aligned
#pragma unroll
    for (int oi = 0; oi < 4; ++oi) {
      int o = o0 + 4 * og + oi;            // c = h*32 + d
      int h = o >> 5, d = o & 31;
      ushort4 r;
      r.x = rne_bf16(acc[oi][0] + ba[oi]);
      r.y = rne_bf16(acc[oi][1] + ba[oi]);
      r.z = rne_bf16(acc[oi][2] + ba[oi]);
      r.w = rne_bf16(acc[oi][3] + ba[oi]);
      size_t off = (size_t)h * 32 * L
                 + ((size_t)(m >> 5) * 2 + (d >> 4)) * 512
                 + (size_t)(d & 15) * 32 + ((m >> 3) & 3) * 8 + (m & 7);
      *(ushort4*)&dst[off] = r;
    }
  }
}

// ---------------- MFMA flash attention, S^T form, software-pipelined K, m-split
// Accumulates UNNORMALIZED O into onum[a][c][L] and row-sums into lsum[a][h][L].
#define PSTR 72
__global__ __launch_bounds__(256, 4) void attn_mfma_kernel(
    const ushort* __restrict__ qb, const ushort* __restrict__ kb,
    const ushort* __restrict__ vb, float* __restrict__ onum,
    float* __restrict__ lsum, int L, int msplit)
{
  __shared__ __align__(16) ushort P[4][16][PSTR];
  int t = threadIdx.x;
  int wave = t >> 6, lane = t & 63;
  int col = lane & 15, quad = lane >> 4;
  int head = blockIdx.y;
  int anchor = blockIdx.z / msplit, mpart = blockIdx.z % msplit;
  int l = blockIdx.x * 64 + wave * 16;
  int mlen = L / msplit, mbase = mpart * mlen;

  const ushort* qh = qb + (size_t)head * L * 32;
  const ushort* kh = kb + ((size_t)anchor * 4 + head) * L * 32;
  const ushort* vh = vb + ((size_t)anchor * 4 + head) * 32 * L;

  bf16x8 qf = *(const bf16x8*)(qh + (size_t)(l + col) * 32 + quad * 8);
  const ushort* kbase = kh + col * 32 + quad * 8;     // + m*32
  const ushort* vbase = vh + col * 32 + quad * 8;     // + (m>>5)*1024 + mc*1024 + db*512

  f32x4 od0 = {0.f,0.f,0.f,0.f};   // O[l-local][d 0..16)
  f32x4 od1 = {0.f,0.f,0.f,0.f};   // O[l-local][d 16..32)
  float ls = 0.f;
  ushort* Pw = &P[wave][0][0];
  const f32x4 z = {0.f,0.f,0.f,0.f};

  // prologue: K tile 0
  const ushort* kp0 = kbase + (size_t)mbase * 32;
  bf16x8 k0 = *(const bf16x8*)(kp0);
  bf16x8 k1 = *(const bf16x8*)(kp0 + 512);
  bf16x8 k2 = *(const bf16x8*)(kp0 + 1024);
  bf16x8 k3 = *(const bf16x8*)(kp0 + 1536);

  for (int mo = 0; mo < mlen; mo += 64) {
    int m0 = mbase + mo;
    // V for CURRENT tile (consumed late -> natural prefetch distance)
    const ushort* vp = vbase + ((size_t)(m0 >> 5)) * 1024;
    bf16x8 v00 = *(const bf16x8*)(vp);            // d 0..15,  m-chunk 0
    bf16x8 v01 = *(const bf16x8*)(vp + 1024);     // d 0..15,  m-chunk 1
    bf16x8 v10 = *(const bf16x8*)(vp + 512);      // d 16..31, m-chunk 0
    bf16x8 v11 = *(const bf16x8*)(vp + 1536);     // d 16..31, m-chunk 1
    // K for NEXT tile
    int mn = (mo + 64 < mlen) ? (m0 + 64) : mbase;
    const ushort* kpn = kbase + (size_t)mn * 32;
    bf16x8 kn0 = *(const bf16x8*)(kpn);
    bf16x8 kn1 = *(const bf16x8*)(kpn + 512);
    bf16x8 kn2 = *(const bf16x8*)(kpn + 1024);
    bf16x8 kn3 = *(const bf16x8*)(kpn + 1536);

    // S^T tiles: D[m-within-tile][l], A=K, B=Q
    f32x4 s0 = __builtin_amdgcn_mfma_f32_16x16x32_bf16(k0, qf, z, 0, 0, 0);
    f32x4 s1 = __builtin_amdgcn_mfma_f32_16x16x32_bf16(k1, qf, z, 0, 0, 0);
    f32x4 s2 = __builtin_amdgcn_mfma_f32_16x16x32_bf16(k2, qf, z, 0, 0, 0);
    f32x4 s3 = __builtin_amdgcn_mfma_f32_16x16x32_bf16(k3, qf, z, 0, 0, 0);

    // p = exp(s) -> RNE bf16 pack; sum the ROUNDED values (consistent norm)
    float sv[4][4] = {{s0.x,s0.y,s0.z,s0.w},{s1.x,s1.y,s1.z,s1.w},
                      {s2.x,s2.y,s2.z,s2.w},{s3.x,s3.y,s3.z,s3.w}};
#pragma unroll
    for (int j = 0; j < 4; ++j) {
      uint u0 = pk2_bf16(__expf(sv[j][0]), __expf(sv[j][1]));
      uint u1 = pk2_bf16(__expf(sv[j][2]), __expf(sv[j][3]));
      ls += __uint_as_float(u0 << 16) + __uint_as_float(u0 & 0xffff0000u)
          + __uint_as_float(u1 << 16) + __uint_as_float(u1 & 0xffff0000u);
      uint2 dw; dw.x = u0; dw.y = u1;
      *(uint2*)&Pw[col * PSTR + 16 * j + quad * 4] = dw;
    }

    // P A-frags (row l=col-local, k-chunks of m) and PV
    bf16x8 p0 = *(const bf16x8*)(&Pw[col * PSTR + quad * 8]);
    bf16x8 p1 = *(const bf16x8*)(&Pw[col * PSTR + 32 + quad * 8]);
    od0 = __builtin_amdgcn_mfma_f32_16x16x32_bf16(p0, v00, od0, 0, 0, 0);
    od0 = __builtin_amdgcn_mfma_f32_16x16x32_bf16(p1, v01, od0, 0, 0, 0);
    od1 = __builtin_amdgcn_mfma_f32_16x16x32_bf16(p0, v10, od1, 0, 0, 0);
    od1 = __builtin_amdgcn_mfma_f32_16x16x32_bf16(p1, v11, od1, 0, 0, 0);

    k0 = kn0; k1 = kn1; k2 = kn2; k3 = kn3;
  }

  // row-sum butterfly over quads (lane bits 4,5)
  ls += __shfl_xor(ls, 16); ls += __shfl_xor(ls, 32);
  float* lsp = lsum + ((size_t)anchor * 4 + head) * L;
  if (quad == 0) atomicAdd(&lsp[l + col], ls);
  float* on = onum + (size_t)anchor * 128 * L + (size_t)(head * 32) * L;
#pragma unroll
  for (int r = 0; r < 4; ++r) {
    atomicAdd(&on[(size_t)col * L + l + quad * 4 + r],        od0[r]);
    atomicAdd(&on[(size_t)(16 + col) * L + l + quad * 4 + r], od1[r]);
  }
}

// ---------------- normalize: A[c][l] = (1/3) * sum_a onum[a][c][l] / lsum[a][h][l]
__global__ __launch_bounds__(256) void norm_kernel(
    const float* __restrict__ on4,  const float* __restrict__ ls4,  float* __restrict__ a4,
    const float* __restrict__ on8,  const float* __restrict__ ls8,  float* __restrict__ a8,
    const float* __restrict__ on16, const float* __restrict__ ls16, float* __restrict__ a16)
{
  int i = blockIdx.x * 256 + threadIdx.x;   // float4 index
  const float* on; const float* ls; float* ax; int L;
  if (i < 131072)      { on = on4;  ls = ls4;  ax = a4;  L = 4096; }
  else if (i < 163840) { i -= 131072; on = on8;  ls = ls8;  ax = a8;  L = 1024; }
  else                 { i -= 163840; on = on16; ls = ls16; ax = a16; L = 256; }
  int e = i * 4;
  int c = e / L, l = e % L;
  int h = c >> 5;
  float ax0 = 0.f, ax1 = 0.f, ax2 = 0.f, ax3 = 0.f;
#pragma unroll
  for (int a = 0; a < 3; ++a) {
    float4 o = *(const float4*)&on[(size_t)(a * 128 + c) * L + l];
    float4 s = *(const float4*)&ls[(size_t)(a * 4 + h) * L + l];
    ax0 += o.x / s.x; ax1 += o.y / s.y; ax2 += o.z / s.z; ax3 += o.w / s.w;
  }
  const float third = 1.f / 3.f;
  float4 r = make_float4(ax0 * third, ax1 * third, ax2 * third, ax3 * third);
  *(float4*)&ax[e] = r;
}

// ---------------- fused bilinear upsample + combined 1x1 conv
__global__ __launch_bounds__(256) void fuse_kernel(
    const float* __restrict__ a16, const float* __restrict__ a8,
    const float* __restrict__ a4, const float* __restrict__ Wc,
    const float* __restrict__ bc, float* __restrict__ outp)
{
  __shared__ float Wt[32][132];
  __shared__ float Xs[32][64];
  __shared__ float patch[32][16];
  int t = threadIdx.x;
  int px0 = blockIdx.x * 8, py0 = blockIdx.y * 8;
  int og = t >> 3, pg = t & 7;
  float acc[4][8] = {};
  for (int ch = 0; ch < 12; ++ch) {
    int sci = ch >> 2;
    int coff = (ch & 3) * 32;
    int ssz; const float* src; float sf;
    if (sci == 0)      { ssz = 16; src = a16; sf = 1.f / 16.f; }
    else if (sci == 1) { ssz = 32; src = a8;  sf = 1.f / 8.f; }
    else               { ssz = 64; src = a4;  sf = 1.f / 4.f; }
    float sx0 = (px0 + 0.5f) * sf - 0.5f;
    float sy0 = (py0 + 0.5f) * sf - 0.5f;
    int x0f = (int)floorf(sx0);
    int y0f = (int)floorf(sy0);
    __syncthreads();
    { // stage Wc chunk -> Wt[k][o]
      int o = t >> 1, ki = (t & 1) * 16;
      const float* wp = Wc + o * 384 + ch * 32 + ki;
#pragma unroll
      for (int j = 0; j < 16; j += 4) {
        float4 w4 = *(const float4*)(wp + j);
        Wt[ki + j + 0][o] = w4.x; Wt[ki + j + 1][o] = w4.y;
        Wt[ki + j + 2][o] = w4.z; Wt[ki + j + 3][o] = w4.w;
      }
    }
    if (t < 128) { // stage 4x4 source patch for 32 channels
      int c = t >> 2, ry = t & 3;
      int yy = min(max(y0f + ry, 0), ssz - 1);
      const float* sp = src + (size_t)(coff + c) * ssz * ssz + yy * ssz;
#pragma unroll
      for (int rx = 0; rx < 4; ++rx) {
        int xx = min(max(x0f + rx, 0), ssz - 1);
        patch[c][ry * 4 + rx] = sp[xx];
      }
    }
    __syncthreads();
    { // bilinear -> Xs[k][p]
      int p = t & 63, cg = t >> 6;
      int px = p & 7, py = p >> 3;
      float sx = (px0 + px + 0.5f) * sf - 0.5f;
      float sy = (py0 + py + 0.5f) * sf - 0.5f;
      int xi = (int)floorf(sx), yi = (int)floorf(sy);
      float fx = sx - xi, fy = sy - yi;
      int lx = xi - x0f, ly = yi - y0f;
      int lx1 = min(xi + 1, ssz - 1) - x0f;
      int ly1 = min(yi + 1, ssz - 1) - y0f;
      float w00 = (1.f - fy) * (1.f - fx), w01 = (1.f - fy) * fx;
      float w10 = fy * (1.f - fx), w11 = fy * fx;
#pragma unroll
      for (int j = 0; j < 8; ++j) {
        int k = 8 * cg + j;
        float v = w00 * patch[k][ly * 4 + lx] + w01 * patch[k][ly * 4 + lx1]
                + w10 * patch[k][ly1 * 4 + lx] + w11 * patch[k][ly1 * 4 + lx1];
        Xs[k][p] = v;
      }
    }
    __syncthreads();
#pragma unroll 8
    for (int k = 0; k < 32; ++k) {
      float4 w4 = *(const float4*)&Wt[k][4 * og];
      float4 xa4 = *(const float4*)&Xs[k][8 * pg];
      float4 xb4 = *(const float4*)&Xs[k][8 * pg + 4];
      float wa[4] = {w4.x, w4.y, w4.z, w4.w};
      float xv[8] = {xa4.x, xa4.y, xa4.z, xa4.w, xb4.x, xb4.y, xb4.z, xb4.w};
#pragma unroll
      for (int r = 0; r < 4; ++r)
#pragma unroll
        for (int c = 0; c < 8; ++c)
          acc[r][c] = fmaf(wa[r], xv[c], acc[r][c]);
    }
  }
#pragma unroll
  for (int oi = 0; oi < 4; ++oi) {
    int o = 4 * og + oi;
    float bb = bc[o];
    float4 r0 = make_float4(acc[oi][0] + bb, acc[oi][1] + bb, acc[oi][2] + bb, acc[oi][3] + bb);
    float4 r1 = make_float4(acc[oi][4] + bb, acc[oi][5] + bb, acc[oi][6] + bb, acc[oi][7] + bb);
    float* op = outp + (size_t)o * 65536 + (py0 + pg) * 256 + px0;
    *(float4*)op = r0; *(float4*)(op + 4) = r1;
  }
}

extern "C" void kernel_launch(void* const* d_in, const int* in_sizes, int n_in,
                              void* d_out, int out_size, void* d_ws, size_t ws_size,
                              hipStream_t stream) {
  const float* query    = (const float*)d_in[0];
  const float* keys     = (const float*)d_in[1];
  const float* values   = (const float*)d_in[2];
  const float* wq       = (const float*)d_in[3];
  const float* bq       = (const float*)d_in[4];
  const float* wk       = (const float*)d_in[5];
  const float* bk       = (const float*)d_in[6];
  const float* wv       = (const float*)d_in[7];
  const float* bv       = (const float*)d_in[8];
  const float* fusion_w = (const float*)d_in[9];
  const float* fusion_b = (const float*)d_in[10];
  const float* out_w    = (const float*)d_in[11];
  const float* out_b    = (const float*)d_in[12];
  float* wsf  = (float*)d_ws;
  float* outp = (float*)d_out;

  // workspace layout (float units)
  const size_t P4   = 0;        // pooled s=4 [7][128][4096] (dead after proj)
  const size_t P8   = 3670016;  // pooled s=8
  const size_t P16  = 4587520;  // pooled s=16
  // ON/LS alias the pool region (zeroed after proj, stream-ordered):
  const size_t ON4  = 0;        // [3][128][4096] = 1572864
  const size_t LS4  = 1572864;  // [3][4][4096]   = 49152
  const size_t ON8  = 1622016;  // 393216
  const size_t LS8  = 2015232;  // 12288
  const size_t ON16 = 2027520;  // 98304
  const size_t LS16 = 2125824;  // 3072  -> end 2128896 (< P8 offset, safe)
  const size_t QB4  = 4816896;  // bf16 [4][4096][32]
  const size_t KB4  = 5079040;  // bf16 [3][4][4096][32]
  const size_t VB4  = 5865472;  // bf16 [3][4][32*4096] (frag chunks)
  const size_t QB8  = 6651904;
  const size_t KB8  = 6717440;
  const size_t VB8  = 6914048;
  const size_t QB16 = 7110656;
  const size_t KB16 = 7127040;
  const size_t VB16 = 7176192;
  const size_t A4   = 7225344;  // fp32 [128][4096]
  const size_t A8   = 7749632;
  const size_t A16  = 7880704;
  const size_t WC   = 7913472;
  const size_t BC   = 7962624;

  precomp_kernel<<<(128*384 + 128 + 255) / 256, 256, 0, stream>>>(
      fusion_w, fusion_b, out_w, out_b, wsf + WC, wsf + BC);
  pool4_kernel<<<7*128*4096/256, 256, 0, stream>>>(query, keys, values, wsf + P4);
  pool2_kernel<<<7*128*1024/256, 256, 0, stream>>>(wsf + P4, wsf + P8, 32);
  pool2_kernel<<<7*128*256/256,  256, 0, stream>>>(wsf + P8, wsf + P16, 16);

  const float qsc = 0.17677669529663687f;  // 1/sqrt(32)
  proj_kernel<<<dim3(64, 2, 7), 256, 0, stream>>>(wsf + P4,
      (ushort*)(wsf + QB4), (ushort*)(wsf + KB4), (ushort*)(wsf + VB4),
      wq, bq, wk, bk, wv, bv, 2, 4096, qsc);
  proj_kernel<<<dim3(16, 2, 7), 256, 0, stream>>>(wsf + P8,
      (ushort*)(wsf + QB8), (ushort*)(wsf + KB8), (ushort*)(wsf + VB8),
      wq, bq, wk, bk, wv, bv, 1, 1024, qsc);
  proj_kernel<<<dim3(4, 2, 7), 256, 0, stream>>>(wsf + P16,
      (ushort*)(wsf + QB16), (ushort*)(wsf + KB16), (ushort*)(wsf + VB16),
      wq, bq, wk, bk, wv, bv, 0, 256, qsc);

  // zero ON/LS accumulators (pool region dead after proj; stream-ordered)
  hipMemsetAsync(wsf + ON4, 0, (size_t)2128896 * sizeof(float), stream);

  attn_mfma_kernel<<<dim3(64, 4, 12), 256, 0, stream>>>(
      (const ushort*)(wsf + QB4), (const ushort*)(wsf + KB4),
      (const ushort*)(wsf + VB4), wsf + ON4, wsf + LS4, 4096, 4);
  attn_mfma_kernel<<<dim3(16, 4, 12), 256, 0, stream>>>(
      (const ushort*)(wsf + QB8), (const ushort*)(wsf + KB8),
      (const ushort*)(wsf + VB8), wsf + ON8, wsf + LS8, 1024, 4);
  attn_mfma_kernel<<<dim3(4, 4, 12), 256, 0, stream>>>(
      (const ushort*)(wsf + QB16), (const ushort*)(wsf + KB16),
      (const ushort*)(wsf + VB16), wsf + ON16, wsf + LS16, 256, 4);

  norm_kernel<<<672, 256, 0, stream>>>(
      wsf + ON4, wsf + LS4, wsf + A4,
      wsf + ON8, wsf + LS8, wsf + A8,
      wsf + ON16, wsf + LS16, wsf + A16);

  fuse_kernel<<<dim3(32, 32), 256, 0, stream>>>(
      wsf + A16, wsf + A8, wsf + A4, wsf + WC, wsf + BC, outp);
}